// Round 4
// baseline (3823.656 us; speedup 1.0000x reference)
//
#include <hip/hip_runtime.h>
#include <cstdint>

#define GG   29
#define GG2  841
#define GG3  24389
#define DD   15
#define DD3  3375
#define SS   48
#define CC   16
#define NVOX (SS*SS*SS)        // 110592
#define FT_ELEMS (NVOX*CC)     // 1769472
#define WXY  20                // window width in x,y (voxels used)
#define WROW 21                // padded row stride in float4 (bank decorrelation)
#define WZC  6                 // window planes per z-chunk
#define WPL  (WROW*WXY)        // 420 float4 per plane
#define WELE4 (WXY*WXY*WZC)    // 2400 staged float4
#define DCH  8                 // d-chunk for fused grid conv
#define NCH  ((DD3 + DCH - 1) / DCH)   // 422

#define MW0 (1.0f/9.0f)
#define MW1 (2.0f/9.0f)
#define MW2 (3.0f/9.0f)

__device__ __forceinline__ int clampi(int v, int lo, int hi) {
    return min(max(v, lo), hi);
}

__device__ __forceinline__ float4 f4min3(float4 a, float4 b, float4 c) {
    return make_float4(fminf(fminf(a.x,b.x),c.x), fminf(fminf(a.y,b.y),c.y),
                       fminf(fminf(a.z,b.z),c.z), fminf(fminf(a.w,b.w),c.w));
}
__device__ __forceinline__ void f4acc(float4& o, float w, float4 a) {
    o.x += w*a.x; o.y += w*a.y; o.z += w*a.z; o.w += w*a.w;
}

// ---------------- transpose [C,S,S,S] -> [4 groups][S^3] float4 (moving image) ----------------
__global__ void __launch_bounds__(256) k_transpose4(const float* __restrict__ f,
                                                    float* __restrict__ ft) {
    int v = blockIdx.x * 256 + threadIdx.x;      // < NVOX (grid sized exactly)
    int cg4 = blockIdx.y;                        // 0..3
    float4 o = make_float4(f[(4*cg4+0)*NVOX + v], f[(4*cg4+1)*NVOX + v],
                           f[(4*cg4+2)*NVOX + v], f[(4*cg4+3)*NVOX + v]);
    ((float4*)ft)[(size_t)cg4 * NVOX + v] = o;
}

// ---------------- K1: deeds cost volume, float4 channel-quads, padded window rows ----------------
template<int JZ0, int NJZ>
__device__ __forceinline__ void cost_chunk(const float4* __restrict__ f5f4,
                                           float4* win, const float4* fixs4,
                                           int tid, float pzb, int xb, int yb,
                                           int orel, float wx, float wy,
                                           bool active, float (&acc)[15]) {
    float pz0 = fminf(fmaxf(pzb + 1.28f * (float)JZ0, 0.0f), 47.0f);
    int zb = min((int)floorf(pz0), SS - WZC);   // <= 42
    int   z0r[NJZ];
    float wzs[NJZ];
    #pragma unroll
    for (int k = 0; k < NJZ; ++k) {
        float pz = fminf(fmaxf(pzb + 1.28f * (float)(JZ0 + k), 0.0f), 47.0f);
        int z0 = min((int)floorf(pz), 46);
        z0r[k] = z0 - zb;          // in [0,4]
        wzs[k] = pz - (float)z0;
    }

    // staging addresses + padded LDS positions, hoisted across channel passes
    int vox[10];
    int ldsp[10];
    #pragma unroll
    for (int k = 0; k < 10; ++k) {
        int idx = tid + (k << 8);
        if (idx < WELE4) {
            int lz  = idx / 400;
            int rem = idx - lz * 400;
            int ly  = rem / 20;
            int lx  = rem - ly * 20;
            vox[k]  = ((zb + lz) * SS + (yb + ly)) * SS + (xb + lx);
            ldsp[k] = lz * WPL + ly * WROW + lx;
        }
    }

    auto bilin = [&](int zr) -> float4 {
        const float4* P = win + zr * WPL + orel;
        float4 a = P[0], b = P[1], c = P[WROW], d = P[WROW+1];
        float r0x = a.x + wx*(b.x-a.x), r0y = a.y + wx*(b.y-a.y);
        float r0z = a.z + wx*(b.z-a.z), r0w = a.w + wx*(b.w-a.w);
        float r1x = c.x + wx*(d.x-c.x), r1y = c.y + wx*(d.y-c.y);
        float r1z = c.z + wx*(d.z-c.z), r1w = c.w + wx*(d.w-c.w);
        return make_float4(r0x + wy*(r1x-r0x), r0y + wy*(r1y-r0y),
                           r0z + wy*(r1z-r0z), r0w + wy*(r1w-r0w));
    };

    #pragma unroll 1
    for (int cg4 = 0; cg4 < 4; ++cg4) {
        const float4* src = f5f4 + (size_t)cg4 * NVOX;
        #pragma unroll
        for (int k = 0; k < 10; ++k) {
            int idx = tid + (k << 8);
            if (idx < WELE4) win[ldsp[k]] = src[vox[k]];
        }
        __syncthreads();

        if (active) {
            float4 fx = fixs4[cg4];
            float4 pA = make_float4(0.f,0.f,0.f,0.f), pB = pA;
            int zprev = -99;
            #pragma unroll
            for (int k = 0; k < NJZ; ++k) {
                int zr = z0r[k]; float wz = wzs[k];
                if (zr != zprev) {
                    if (zr == zprev + 1) pA = pB;
                    else                 pA = bilin(zr);
                    pB = bilin(zr + 1);
                    zprev = zr;
                }
                float mx = pA.x + wz*(pB.x-pA.x);
                float my = pA.y + wz*(pB.y-pA.y);
                float mz = pA.z + wz*(pB.z-pA.z);
                float mw = pA.w + wz*(pB.w-pA.w);
                float dx = fx.x - mx, dy = fx.y - my, dz = fx.z - mz, dw = fx.w - mw;
                acc[JZ0 + k] += dx*dx + dy*dy + dz*dz + dw*dw;
            }
        }
        __syncthreads();
    }
}

__global__ void __launch_bounds__(256, 4) k_cost5(const float* __restrict__ f5t,   // float4 [4][NVOX]
                                                  const float* __restrict__ feat00,// [C][NVOX]
                                                  const float* __restrict__ alpha,
                                                  float* __restrict__ dc) {
    __shared__ float4 win[WPL * WZC];    // 2520 float4 = 40.3 KB (padded rows)
    __shared__ float4 fixs4[4];

    int tid = threadIdx.x;
    int g = blockIdx.x;
    int gx = g % GG; int gy = (g / GG) % GG; int gz = g / GG2;

    if (tid < CC) {
        int giv[3] = {gx, gy, gz};
        int i0[3]; float w[3];
        #pragma unroll
        for (int a = 0; a < 3; ++a) {
            float cgv = (2.0f * giv[a] + 1.0f) / 29.0f - 1.0f;
            float p = ((cgv + 1.0f) * 48.0f - 1.0f) * 0.5f;
            p = fminf(fmaxf(p, 0.0f), 47.0f);
            float fl = floorf(p);
            i0[a] = (int)fl; w[a] = p - fl;
        }
        int x0 = i0[0], y0 = i0[1], z0 = i0[2];
        int x1 = min(x0 + 1, 47), y1 = min(y0 + 1, 47), z1 = min(z0 + 1, 47);
        float wx = w[0], wy = w[1], wz = w[2];
        float ux = 1.0f - wx, uy = 1.0f - wy, uz = 1.0f - wz;
        const float* fc = feat00 + (size_t)tid * NVOX;
        int zy00 = (z0 * SS + y0) * SS, zy01 = (z0 * SS + y1) * SS;
        int zy10 = (z1 * SS + y0) * SS, zy11 = (z1 * SS + y1) * SS;
        ((float*)fixs4)[tid] =
              uz*uy*ux * fc[zy00 + x0] + uz*uy*wx * fc[zy00 + x1]
            + uz*wy*ux * fc[zy01 + x0] + uz*wy*wx * fc[zy01 + x1]
            + wz*uy*ux * fc[zy10 + x0] + wz*uy*wx * fc[zy10 + x1]
            + wz*wy*ux * fc[zy11 + x0] + wz*wy*wx * fc[zy11 + x1];
    }

    float pxb = 24.0f * (float)(2 * gx + 1) / 29.0f - 9.46f;
    float pyb = 24.0f * (float)(2 * gy + 1) / 29.0f - 9.46f;
    float pzb = 24.0f * (float)(2 * gz + 1) / 29.0f - 9.46f;
    int xb = min((int)floorf(fminf(fmaxf(pxb, 0.0f), 47.0f)), SS - WXY);
    int yb = min((int)floorf(fminf(fmaxf(pyb, 0.0f), 47.0f)), SS - WXY);

    bool active = tid < 225;
    int jx = tid % 15, jy = tid / 15;
    float px = fminf(fmaxf(pxb + 1.28f * (float)jx, 0.0f), 47.0f);
    float py = fminf(fmaxf(pyb + 1.28f * (float)jy, 0.0f), 47.0f);
    int x0 = min((int)floorf(px), 46);
    int y0 = min((int)floorf(py), 46);
    float wx = px - (float)x0;
    float wy = py - (float)y0;
    int orel = (y0 - yb) * WROW + (x0 - xb);

    float acc[15];
    #pragma unroll
    for (int k = 0; k < 15; ++k) acc[k] = 0.0f;

    const float4* f5f4 = (const float4*)f5t;
    cost_chunk<0, 4>(f5f4, win, fixs4, tid, pzb, xb, yb, orel, wx, wy, active, acc);
    cost_chunk<4, 4>(f5f4, win, fixs4, tid, pzb, xb, yb, orel, wx, wy, active, acc);
    cost_chunk<8, 4>(f5f4, win, fixs4, tid, pzb, xb, yb, orel, wx, wy, active, acc);
    cost_chunk<12,3>(f5f4, win, fixs4, tid, pzb, xb, yb, orel, wx, wy, active, acc);

    float a0 = alpha[0], a1 = alpha[1];
    if (active) {
        float* dcrow = dc + (size_t)g * DD3;
        #pragma unroll
        for (int k = 0; k < 15; ++k) dcrow[k * 225 + tid] = a1 + a0 * acc[k];
    }
}

// ------------- minavg_disp, z-column register version -------------
__device__ __forceinline__ void minavg_cols(float* U, float* V, float (&v)[15],
                                            int tid, float* __restrict__ outrow) {
    // P1: z-min (pad-replicate) 15 -> 19 (slot 19 dup for vector fill)
    if (tid < 225) {
        float m[20];
        #pragma unroll
        for (int zi = 0; zi < 20; ++zi)
            m[zi] = fminf(fminf(v[clampi(zi-3,0,14)], v[clampi(zi-2,0,14)]),
                          v[clampi(zi-1,0,14)]);
        float4* u4 = (float4*)&U[tid*20];
        const float4* m4 = (const float4*)m;
        #pragma unroll
        for (int q = 0; q < 5; ++q) u4[q] = m4[q];
    }
    __syncthreads();
    // P2: y-min (pad-replicate): out cols (sx in 15, yi in 19) = 285
    for (int c = tid; c < 285; c += 256) {
        int sx = c % 15, yi = c / 15;
        const float4* A = (const float4*)&U[(clampi(yi-3,0,14)*15 + sx)*20];
        const float4* B = (const float4*)&U[(clampi(yi-2,0,14)*15 + sx)*20];
        const float4* Cc= (const float4*)&U[(clampi(yi-1,0,14)*15 + sx)*20];
        float4* vv = (float4*)&V[c*20];
        #pragma unroll
        for (int q = 0; q < 5; ++q) vv[q] = f4min3(A[q], B[q], Cc[q]);
    }
    __syncthreads();
    // P3: x-min (pad-replicate) + z-conv: out cols (xi in 19, yi in 19) = 361
    for (int c = tid; c < 361; c += 256) {
        int xi = c % 19, yi = c / 19;
        int s0 = clampi(xi-3,0,14), s1 = clampi(xi-2,0,14), s2 = clampi(xi-1,0,14);
        const float4* A = (const float4*)&V[(yi*15 + s0)*20];
        const float4* B = (const float4*)&V[(yi*15 + s1)*20];
        const float4* Cc= (const float4*)&V[(yi*15 + s2)*20];
        float m[20];
        float4* m4 = (float4*)m;
        #pragma unroll
        for (int q = 0; q < 5; ++q) m4[q] = f4min3(A[q], B[q], Cc[q]);
        float cz[16];
        #pragma unroll
        for (int zi = 0; zi < 15; ++zi)
            cz[zi] = MW0*(m[zi] + m[zi+4]) + MW1*(m[zi+1] + m[zi+3]) + MW2*m[zi+2];
        cz[15] = cz[14];
        float4* u4 = (float4*)&U[c*16];
        const float4* c4 = (const float4*)cz;
        #pragma unroll
        for (int q = 0; q < 4; ++q) u4[q] = c4[q];
    }
    __syncthreads();
    // P4: y-conv (interior 5-tap): out cols (xi in 19, yi in 15) = 285
    for (int c = tid; c < 285; c += 256) {
        int xi = c % 19, yi = c / 19;
        float4 o0 = make_float4(0.f,0.f,0.f,0.f), o1 = o0, o2 = o0, o3 = o0;
        const float W[5] = {MW0, MW1, MW2, MW1, MW0};
        #pragma unroll
        for (int t = 0; t < 5; ++t) {
            const float4* A = (const float4*)&U[((yi+t)*19 + xi)*16];
            float w = W[t];
            f4acc(o0, w, A[0]); f4acc(o1, w, A[1]);
            f4acc(o2, w, A[2]); f4acc(o3, w, A[3]);
        }
        float4* vv = (float4*)&V[c*16];
        vv[0] = o0; vv[1] = o1; vv[2] = o2; vv[3] = o3;
    }
    __syncthreads();
    // P5: x-conv (interior 5-tap): out cols (xi in 15, yi in 15) = 225
    if (tid < 225) {
        int xi = tid % 15, yi = tid / 15;
        float4 o0 = make_float4(0.f,0.f,0.f,0.f), o1 = o0, o2 = o0, o3 = o0;
        const float W[5] = {MW0, MW1, MW2, MW1, MW0};
        #pragma unroll
        for (int t = 0; t < 5; ++t) {
            const float4* A = (const float4*)&V[(yi*19 + xi + t)*16];
            float w = W[t];
            f4acc(o0, w, A[0]); f4acc(o1, w, A[1]);
            f4acc(o2, w, A[2]); f4acc(o3, w, A[3]);
        }
        float4* u4 = (float4*)&U[tid*16];
        u4[0] = o0; u4[1] = o1; u4[2] = o2; u4[3] = o3;
    }
    __syncthreads();
    // P6: transpose back to z-major layout, coalesced global write
    for (int d = tid; d < DD3; d += 256)
        outrow[d] = U[(d % 225)*16 + d/225];
}

// ---------------- K2: minavg_disp of dc -> c ----------------
__global__ void __launch_bounds__(256) k_minavg2(const float* __restrict__ in, float* out) {
    __shared__ __align__(16) float U[5776];
    __shared__ __align__(16) float V[5700];
    int tid = threadIdx.x;
    size_t base = (size_t)blockIdx.x * DD3;
    float v[15];
    if (tid < 225) {
        #pragma unroll
        for (int z = 0; z < 15; ++z) v[z] = in[base + z*225 + tid];
    }
    minavg_cols(U, V, v, tid, out + base);
}

// ---------------- fused grid x-conv + y-conv, per (gz, d-chunk) plane tile ----------------
// In-place safe: each (gz, chunk) region is read and written by exactly one block.
__global__ void __launch_bounds__(256) k_convxy(const float* __restrict__ in,
                                                float* __restrict__ out) {
    __shared__ float T[GG2 * DCH];   // 26.9 KB
    __shared__ float X[GG2 * DCH];   // 26.9 KB  -> 3 blocks/CU
    int tid = threadIdx.x;
    int chunk = blockIdx.x % NCH;    // chunk fast: same-plane blocks adjacent (L2 reuse)
    int gz    = blockIdx.x / NCH;
    int d0 = chunk * DCH;
    size_t pbase = (size_t)gz * GG2 * DD3 + d0;

    for (int idx = tid; idx < GG2 * DCH; idx += 256) {
        int dd = idx & (DCH-1), gp = idx >> 3;
        int d = d0 + dd;
        T[idx] = (d < DD3) ? in[pbase + (size_t)gp * DD3 + dd] : 0.0f;
    }
    __syncthreads();
    // x-conv (over gx; gp = gy*29+gx)
    for (int idx = tid; idx < GG2 * DCH; idx += 256) {
        int dd = idx & (DCH-1), gp = idx >> 3;
        int gx = gp % GG, gy = gp / GG;
        int xm2 = gx-2 < 0 ? 0 : gx-2, xm1 = gx-1 < 0 ? 0 : gx-1;
        int xp1 = gx+1 > 28 ? 28 : gx+1, xp2 = gx+2 > 28 ? 28 : gx+2;
        int rb = gy * GG;
        X[idx] = MW0*(T[(rb+xm2)*DCH+dd] + T[(rb+xp2)*DCH+dd])
               + MW1*(T[(rb+xm1)*DCH+dd] + T[(rb+xp1)*DCH+dd])
               + MW2* T[(rb+gx )*DCH+dd];
    }
    __syncthreads();
    // y-conv + store
    for (int idx = tid; idx < GG2 * DCH; idx += 256) {
        int dd = idx & (DCH-1), gp = idx >> 3;
        int gx = gp % GG, gy = gp / GG;
        int ym2 = gy-2 < 0 ? 0 : gy-2, ym1 = gy-1 < 0 ? 0 : gy-1;
        int yp1 = gy+1 > 28 ? 28 : gy+1, yp2 = gy+2 > 28 ? 28 : gy+2;
        float vv = MW0*(X[(ym2*GG+gx)*DCH+dd] + X[(yp2*GG+gx)*DCH+dd])
                 + MW1*(X[(ym1*GG+gx)*DCH+dd] + X[(yp1*GG+gx)*DCH+dd])
                 + MW2* X[(gy *GG+gx)*DCH+dd];
        int d = d0 + dd;
        if (d < DD3) out[pbase + (size_t)gp * DD3 + dd] = vv;
    }
}

// ---------------- K4: z-conv of t2 + combine with dc + minavg_disp -> c3 ----------------
__global__ void __launch_bounds__(256) k_zcomb2(const float* __restrict__ t2,
                                                const float* __restrict__ dcin,
                                                const float* __restrict__ alpha,
                                                float* c3out) {
    __shared__ __align__(16) float U[5776];
    __shared__ __align__(16) float V[5700];
    int tid = threadIdx.x;
    int g = blockIdx.x;
    int gx = g % GG; int gy = (g / GG) % GG; int gz = g / GG2;
    float a2 = alpha[2], a3 = alpha[3], a4 = alpha[4];
    size_t rb0 = ((size_t)((clampi(gz-2,0,28)*GG + gy)*GG + gx)) * DD3;
    size_t rb1 = ((size_t)((clampi(gz-1,0,28)*GG + gy)*GG + gx)) * DD3;
    size_t rb2 = ((size_t)((gz*GG + gy)*GG + gx)) * DD3;
    size_t rb3 = ((size_t)((clampi(gz+1,0,28)*GG + gy)*GG + gx)) * DD3;
    size_t rb4 = ((size_t)((clampi(gz+2,0,28)*GG + gy)*GG + gx)) * DD3;
    const float* drow = dcin + (size_t)g * DD3;
    float v[15];
    if (tid < 225) {
        #pragma unroll
        for (int z = 0; z < 15; ++z) {
            int d = z*225 + tid;
            float ca = MW0*(t2[rb0+d] + t2[rb4+d]) + MW1*(t2[rb1+d] + t2[rb3+d])
                     + MW2*t2[rb2+d];
            v[z] = a4 + a2 * drow[d] + a3 * ca;
        }
    }
    minavg_cols(U, V, v, tid, c3out + (size_t)g * DD3);
}

// ---------------- K7: z-conv of t4 -> softmax -> cost_soft + pred_xyz ----------------
__global__ void __launch_bounds__(256) k_zsoftmax(const float* __restrict__ t4,
                                                  const float* __restrict__ alpha,
                                                  float* __restrict__ cost,
                                                  float* __restrict__ pred) {
    __shared__ float row[DD3];
    __shared__ float4 red4[256];
    int tid = threadIdx.x;
    int g = blockIdx.x;
    int gx = g % GG; int gy = (g / GG) % GG; int gz = g / GG2;
    float a5 = alpha[5];
    size_t rb0 = ((size_t)((clampi(gz-2,0,28)*GG + gy)*GG + gx)) * DD3;
    size_t rb1 = ((size_t)((clampi(gz-1,0,28)*GG + gy)*GG + gx)) * DD3;
    size_t rb2 = ((size_t)((gz*GG + gy)*GG + gx)) * DD3;
    size_t rb3 = ((size_t)((clampi(gz+1,0,28)*GG + gy)*GG + gx)) * DD3;
    size_t rb4 = ((size_t)((clampi(gz+2,0,28)*GG + gy)*GG + gx)) * DD3;

    float lmax = -3.0e38f;
    for (int d = tid; d < DD3; d += 256) {
        float ca = MW0*(t4[rb0+d] + t4[rb4+d]) + MW1*(t4[rb1+d] + t4[rb3+d]) + MW2*t4[rb2+d];
        float vv = -a5 * ca;
        row[d] = vv;
        lmax = fmaxf(lmax, vv);
    }
    red4[tid].x = lmax;
    __syncthreads();
    for (int s = 128; s > 0; s >>= 1) {
        if (tid < s) red4[tid].x = fmaxf(red4[tid].x, red4[tid + s].x);
        __syncthreads();
    }
    float m = red4[0].x;
    __syncthreads();

    float s0 = 0.f, s1 = 0.f, s2 = 0.f, s3 = 0.f;
    for (int d = tid; d < DD3; d += 256) {
        float p = expf(row[d] - m);
        row[d] = p;
        int jx = d % 15; int r = d / 15; int jy = r % 15; int jz = r / 15;
        s0 += p;
        s1 += p * (0.4f * ((2.0f * jx + 1.0f) / 15.0f - 1.0f));
        s2 += p * (0.4f * ((2.0f * jy + 1.0f) / 15.0f - 1.0f));
        s3 += p * (0.4f * ((2.0f * jz + 1.0f) / 15.0f - 1.0f));
    }
    red4[tid] = make_float4(s0, s1, s2, s3);
    __syncthreads();
    for (int s = 128; s > 0; s >>= 1) {
        if (tid < s) {
            float4 a = red4[tid], b = red4[tid + s];
            red4[tid] = make_float4(a.x + b.x, a.y + b.y, a.z + b.z, a.w + b.w);
        }
        __syncthreads();
    }
    float4 tot = red4[0];
    float inv = 1.0f / tot.x;
    size_t base = (size_t)g * DD3;
    for (int d = tid; d < DD3; d += 256) cost[base + d] = row[d] * inv;
    if (tid == 0) {
        pred[g*3 + 0] = tot.y * inv;
        pred[g*3 + 1] = tot.z * inv;
        pred[g*3 + 2] = tot.w * inv;
    }
}

extern "C" void kernel_launch(void* const* d_in, const int* in_sizes, int n_in,
                              void* d_out, int out_size, void* d_ws, size_t ws_size,
                              hipStream_t stream) {
    const float* feat00 = (const float*)d_in[0];
    const float* feat50 = (const float*)d_in[1];
    const float* alpha  = (const float*)d_in[2];
    float* out = (float*)d_out;
    float* ws  = (float*)d_ws;

    float* ft5  = ws;                            // [4][NVOX] float4 (FT_ELEMS floats)
    float* S0   = ws + FT_ELEMS;                 // dc -> c3 -> t4 (row-local reuse)
    float* DOUT = out;                           // scratch use of output buffer: c -> t2
    float* pred = out + (size_t)GG3 * DD3;

    size_t need = ((size_t)FT_ELEMS + (size_t)GG3 * DD3) * sizeof(float);
    if (ws_size < need) return;  // fail cleanly if workspace too small

    // moving image: voxel-major channel-quad layout for LDS window staging
    k_transpose4<<<dim3(NVOX / 256, 4), 256, 0, stream>>>(feat50, ft5);

    // dc
    k_cost5<<<GG3, 256, 0, stream>>>(ft5, feat00, alpha, S0);
    // c = minavg_disp(dc)
    k_minavg2<<<GG3, 256, 0, stream>>>(S0, DOUT);
    // avg_grid x,y on c (fused, in-place; z-conv folded into next kernel)
    k_convxy<<<GG * NCH, 256, 0, stream>>>(DOUT, DOUT);
    // c3 = minavg_disp(a4 + a2*dc + a3*zconv(t2))
    k_zcomb2<<<GG3, 256, 0, stream>>>(DOUT, S0, alpha, S0);
    // avg_grid x,y on c3 (fused, in-place)
    k_convxy<<<GG * NCH, 256, 0, stream>>>(S0, S0);
    // z-conv + softmax + pred
    k_zsoftmax<<<GG3, 256, 0, stream>>>(S0, alpha, out, pred);
}

// Round 5
// 3017.439 us; speedup vs baseline: 1.2672x; 1.2672x over previous
//
#include <hip/hip_runtime.h>
#include <cstdint>

#define GG   29
#define GG2  841
#define GG3  24389
#define DD   15
#define DD3  3375
#define SS   48
#define CC   16
#define NVOX (SS*SS*SS)        // 110592
#define FT_ELEMS (NVOX*CC)     // 1769472
#define WXY  20                // window width in x,y
#define WZC  6                 // window planes per z-chunk
#define WELE4 (WXY*WXY*WZC)    // 2400 float4
#define DCH16 16               // d-chunk for fused grid conv
#define NCH16 211              // ceil(DD3/16)
#define TST   843              // LDS stride per dd (odd -> bank spread)

#define MW0 (1.0f/9.0f)
#define MW1 (2.0f/9.0f)
#define MW2 (3.0f/9.0f)

__device__ __forceinline__ int clampi(int v, int lo, int hi) {
    return min(max(v, lo), hi);
}

__device__ __forceinline__ float4 f4min3(float4 a, float4 b, float4 c) {
    return make_float4(fminf(fminf(a.x,b.x),c.x), fminf(fminf(a.y,b.y),c.y),
                       fminf(fminf(a.z,b.z),c.z), fminf(fminf(a.w,b.w),c.w));
}
__device__ __forceinline__ void f4acc(float4& o, float w, float4 a) {
    o.x += w*a.x; o.y += w*a.y; o.z += w*a.z; o.w += w*a.w;
}

// ---------------- transpose [C,S,S,S] -> [4 groups][S^3] float4 (moving image) ----------------
__global__ void __launch_bounds__(256) k_transpose4(const float* __restrict__ f,
                                                    float* __restrict__ ft) {
    int v = blockIdx.x * 256 + threadIdx.x;      // < NVOX (grid sized exactly)
    int cg4 = blockIdx.y;                        // 0..3
    float4 o = make_float4(f[(4*cg4+0)*NVOX + v], f[(4*cg4+1)*NVOX + v],
                           f[(4*cg4+2)*NVOX + v], f[(4*cg4+3)*NVOX + v]);
    ((float4*)ft)[(size_t)cg4 * NVOX + v] = o;
}

// ---------------- K1: deeds cost volume, float4 channel-quads, 6-plane z-chunks ----------------
// (round-3 k_cost4, verbatim: LDS-pipe-bound at ~1218 us — structural floor)
template<int JZ0, int NJZ>
__device__ __forceinline__ void cost_chunk(const float4* __restrict__ f5f4,
                                           float4* win, const float4* fixs4,
                                           int tid, float pzb, int xb, int yb,
                                           int orel, float wx, float wy,
                                           bool active, float (&acc)[15]) {
    float pz0 = fminf(fmaxf(pzb + 1.28f * (float)JZ0, 0.0f), 47.0f);
    int zb = min((int)floorf(pz0), SS - WZC);   // <= 42
    int   z0r[NJZ];
    float wzs[NJZ];
    #pragma unroll
    for (int k = 0; k < NJZ; ++k) {
        float pz = fminf(fmaxf(pzb + 1.28f * (float)(JZ0 + k), 0.0f), 47.0f);
        int z0 = min((int)floorf(pz), 46);
        z0r[k] = z0 - zb;          // in [0,4]
        wzs[k] = pz - (float)z0;
    }

    // staging addresses hoisted across channel passes
    int vox[10];
    #pragma unroll
    for (int k = 0; k < 10; ++k) {
        int idx = tid + (k << 8);
        if (idx < WELE4) {
            int lz  = idx / 400;
            int rem = idx - lz * 400;
            int ly  = rem / 20;
            int lx  = rem - ly * 20;
            vox[k] = ((zb + lz) * SS + (yb + ly)) * SS + (xb + lx);
        }
    }

    auto bilin = [&](int zr) -> float4 {
        const float4* P = win + zr * 400 + orel;
        float4 a = P[0], b = P[1], c = P[20], d = P[21];
        float r0x = a.x + wx*(b.x-a.x), r0y = a.y + wx*(b.y-a.y);
        float r0z = a.z + wx*(b.z-a.z), r0w = a.w + wx*(b.w-a.w);
        float r1x = c.x + wx*(d.x-c.x), r1y = c.y + wx*(d.y-c.y);
        float r1z = c.z + wx*(d.z-c.z), r1w = c.w + wx*(d.w-c.w);
        return make_float4(r0x + wy*(r1x-r0x), r0y + wy*(r1y-r0y),
                           r0z + wy*(r1z-r0z), r0w + wy*(r1w-r0w));
    };

    #pragma unroll 1
    for (int cg4 = 0; cg4 < 4; ++cg4) {
        const float4* src = f5f4 + (size_t)cg4 * NVOX;
        #pragma unroll
        for (int k = 0; k < 10; ++k) {
            int idx = tid + (k << 8);
            if (idx < WELE4) win[idx] = src[vox[k]];
        }
        __syncthreads();

        if (active) {
            float4 fx = fixs4[cg4];
            float4 pA = make_float4(0.f,0.f,0.f,0.f), pB = pA;
            int zprev = -99;
            #pragma unroll
            for (int k = 0; k < NJZ; ++k) {
                int zr = z0r[k]; float wz = wzs[k];
                if (zr != zprev) {
                    if (zr == zprev + 1) pA = pB;
                    else                 pA = bilin(zr);
                    pB = bilin(zr + 1);
                    zprev = zr;
                }
                float mx = pA.x + wz*(pB.x-pA.x);
                float my = pA.y + wz*(pB.y-pA.y);
                float mz = pA.z + wz*(pB.z-pA.z);
                float mw = pA.w + wz*(pB.w-pA.w);
                float dx = fx.x - mx, dy = fx.y - my, dz = fx.z - mz, dw = fx.w - mw;
                acc[JZ0 + k] += dx*dx + dy*dy + dz*dz + dw*dw;
            }
        }
        __syncthreads();
    }
}

__global__ void __launch_bounds__(256, 4) k_cost4(const float* __restrict__ f5t,   // float4 [4][NVOX]
                                                  const float* __restrict__ feat00,// [C][NVOX]
                                                  const float* __restrict__ alpha,
                                                  float* __restrict__ dc) {
    __shared__ float4 win[WELE4];        // 38.4 KB
    __shared__ float4 fixs4[4];

    int tid = threadIdx.x;
    int g = blockIdx.x;
    int gx = g % GG; int gy = (g / GG) % GG; int gz = g / GG2;

    if (tid < CC) {
        int giv[3] = {gx, gy, gz};
        int i0[3]; float w[3];
        #pragma unroll
        for (int a = 0; a < 3; ++a) {
            float cgv = (2.0f * giv[a] + 1.0f) / 29.0f - 1.0f;
            float p = ((cgv + 1.0f) * 48.0f - 1.0f) * 0.5f;
            p = fminf(fmaxf(p, 0.0f), 47.0f);
            float fl = floorf(p);
            i0[a] = (int)fl; w[a] = p - fl;
        }
        int x0 = i0[0], y0 = i0[1], z0 = i0[2];
        int x1 = min(x0 + 1, 47), y1 = min(y0 + 1, 47), z1 = min(z0 + 1, 47);
        float wx = w[0], wy = w[1], wz = w[2];
        float ux = 1.0f - wx, uy = 1.0f - wy, uz = 1.0f - wz;
        const float* fc = feat00 + (size_t)tid * NVOX;
        int zy00 = (z0 * SS + y0) * SS, zy01 = (z0 * SS + y1) * SS;
        int zy10 = (z1 * SS + y0) * SS, zy11 = (z1 * SS + y1) * SS;
        ((float*)fixs4)[tid] =
              uz*uy*ux * fc[zy00 + x0] + uz*uy*wx * fc[zy00 + x1]
            + uz*wy*ux * fc[zy01 + x0] + uz*wy*wx * fc[zy01 + x1]
            + wz*uy*ux * fc[zy10 + x0] + wz*uy*wx * fc[zy10 + x1]
            + wz*wy*ux * fc[zy11 + x0] + wz*wy*wx * fc[zy11 + x1];
    }

    float pxb = 24.0f * (float)(2 * gx + 1) / 29.0f - 9.46f;
    float pyb = 24.0f * (float)(2 * gy + 1) / 29.0f - 9.46f;
    float pzb = 24.0f * (float)(2 * gz + 1) / 29.0f - 9.46f;
    int xb = min((int)floorf(fminf(fmaxf(pxb, 0.0f), 47.0f)), SS - WXY);
    int yb = min((int)floorf(fminf(fmaxf(pyb, 0.0f), 47.0f)), SS - WXY);

    bool active = tid < 225;
    int jx = tid % 15, jy = tid / 15;
    float px = fminf(fmaxf(pxb + 1.28f * (float)jx, 0.0f), 47.0f);
    float py = fminf(fmaxf(pyb + 1.28f * (float)jy, 0.0f), 47.0f);
    int x0 = min((int)floorf(px), 46);
    int y0 = min((int)floorf(py), 46);
    float wx = px - (float)x0;
    float wy = py - (float)y0;
    int orel = (y0 - yb) * WXY + (x0 - xb);

    float acc[15];
    #pragma unroll
    for (int k = 0; k < 15; ++k) acc[k] = 0.0f;

    const float4* f5f4 = (const float4*)f5t;
    cost_chunk<0, 4>(f5f4, win, fixs4, tid, pzb, xb, yb, orel, wx, wy, active, acc);
    cost_chunk<4, 4>(f5f4, win, fixs4, tid, pzb, xb, yb, orel, wx, wy, active, acc);
    cost_chunk<8, 4>(f5f4, win, fixs4, tid, pzb, xb, yb, orel, wx, wy, active, acc);
    cost_chunk<12,3>(f5f4, win, fixs4, tid, pzb, xb, yb, orel, wx, wy, active, acc);

    float a0 = alpha[0], a1 = alpha[1];
    if (active) {
        float* dcrow = dc + (size_t)g * DD3;
        #pragma unroll
        for (int k = 0; k < 15; ++k) dcrow[k * 225 + tid] = a1 + a0 * acc[k];
    }
}

// ------------- minavg_disp, z-column register version -------------
__device__ __forceinline__ void minavg_cols(float* U, float* V, float (&v)[15],
                                            int tid, float* __restrict__ outrow) {
    // P1: z-min (pad-replicate) 15 -> 19 (slot 19 dup for vector fill)
    if (tid < 225) {
        float m[20];
        #pragma unroll
        for (int zi = 0; zi < 20; ++zi)
            m[zi] = fminf(fminf(v[clampi(zi-3,0,14)], v[clampi(zi-2,0,14)]),
                          v[clampi(zi-1,0,14)]);
        float4* u4 = (float4*)&U[tid*20];
        const float4* m4 = (const float4*)m;
        #pragma unroll
        for (int q = 0; q < 5; ++q) u4[q] = m4[q];
    }
    __syncthreads();
    // P2: y-min (pad-replicate): out cols (sx in 15, yi in 19) = 285
    for (int c = tid; c < 285; c += 256) {
        int sx = c % 15, yi = c / 15;
        const float4* A = (const float4*)&U[(clampi(yi-3,0,14)*15 + sx)*20];
        const float4* B = (const float4*)&U[(clampi(yi-2,0,14)*15 + sx)*20];
        const float4* Cc= (const float4*)&U[(clampi(yi-1,0,14)*15 + sx)*20];
        float4* vv = (float4*)&V[c*20];
        #pragma unroll
        for (int q = 0; q < 5; ++q) vv[q] = f4min3(A[q], B[q], Cc[q]);
    }
    __syncthreads();
    // P3: x-min (pad-replicate) + z-conv: out cols (xi in 19, yi in 19) = 361
    for (int c = tid; c < 361; c += 256) {
        int xi = c % 19, yi = c / 19;
        int s0 = clampi(xi-3,0,14), s1 = clampi(xi-2,0,14), s2 = clampi(xi-1,0,14);
        const float4* A = (const float4*)&V[(yi*15 + s0)*20];
        const float4* B = (const float4*)&V[(yi*15 + s1)*20];
        const float4* Cc= (const float4*)&V[(yi*15 + s2)*20];
        float m[20];
        float4* m4 = (float4*)m;
        #pragma unroll
        for (int q = 0; q < 5; ++q) m4[q] = f4min3(A[q], B[q], Cc[q]);
        float cz[16];
        #pragma unroll
        for (int zi = 0; zi < 15; ++zi)
            cz[zi] = MW0*(m[zi] + m[zi+4]) + MW1*(m[zi+1] + m[zi+3]) + MW2*m[zi+2];
        cz[15] = cz[14];
        float4* u4 = (float4*)&U[c*16];
        const float4* c4 = (const float4*)cz;
        #pragma unroll
        for (int q = 0; q < 4; ++q) u4[q] = c4[q];
    }
    __syncthreads();
    // P4: y-conv (interior 5-tap): out cols (xi in 19, yi in 15) = 285
    for (int c = tid; c < 285; c += 256) {
        int xi = c % 19, yi = c / 19;
        float4 o0 = make_float4(0.f,0.f,0.f,0.f), o1 = o0, o2 = o0, o3 = o0;
        const float W[5] = {MW0, MW1, MW2, MW1, MW0};
        #pragma unroll
        for (int t = 0; t < 5; ++t) {
            const float4* A = (const float4*)&U[((yi+t)*19 + xi)*16];
            float w = W[t];
            f4acc(o0, w, A[0]); f4acc(o1, w, A[1]);
            f4acc(o2, w, A[2]); f4acc(o3, w, A[3]);
        }
        float4* vv = (float4*)&V[c*16];
        vv[0] = o0; vv[1] = o1; vv[2] = o2; vv[3] = o3;
    }
    __syncthreads();
    // P5: x-conv (interior 5-tap): out cols (xi in 15, yi in 15) = 225
    if (tid < 225) {
        int xi = tid % 15, yi = tid / 15;
        float4 o0 = make_float4(0.f,0.f,0.f,0.f), o1 = o0, o2 = o0, o3 = o0;
        const float W[5] = {MW0, MW1, MW2, MW1, MW0};
        #pragma unroll
        for (int t = 0; t < 5; ++t) {
            const float4* A = (const float4*)&V[(yi*19 + xi + t)*16];
            float w = W[t];
            f4acc(o0, w, A[0]); f4acc(o1, w, A[1]);
            f4acc(o2, w, A[2]); f4acc(o3, w, A[3]);
        }
        float4* u4 = (float4*)&U[tid*16];
        u4[0] = o0; u4[1] = o1; u4[2] = o2; u4[3] = o3;
    }
    __syncthreads();
    // P6: transpose back to z-major layout, coalesced global write
    for (int d = tid; d < DD3; d += 256)
        outrow[d] = U[(d % 225)*16 + d/225];
}

// ---------------- K2: minavg_disp of dc -> c ----------------
__global__ void __launch_bounds__(256) k_minavg2(const float* __restrict__ in, float* out) {
    __shared__ __align__(16) float U[5776];
    __shared__ __align__(16) float V[5700];
    int tid = threadIdx.x;
    size_t base = (size_t)blockIdx.x * DD3;
    float v[15];
    if (tid < 225) {
        #pragma unroll
        for (int z = 0; z < 15; ++z) v[z] = in[base + z*225 + tid];
    }
    minavg_cols(U, V, v, tid, out + base);
}

// ---------------- fused grid x+y conv, coalesced [gp][dd] I/O, LDS [dd][gp] ----------------
// block = (gz, d-chunk of 16). Thread owns one (gx,dd) column: x-conv from LDS
// (29 static-unrolled 5-tap), y-conv in registers. Bitwise == conv_grid axis0;axis1.
// In-place safe: all reads staged to LDS before any write; block regions disjoint.
__global__ void __launch_bounds__(512) k_convxy2(const float* __restrict__ in,
                                                 float* __restrict__ out) {
    __shared__ float T[DCH16 * TST];     // 53.9 KB -> 2 blocks/CU
    int tid = threadIdx.x;
    int chunk = blockIdx.x % NCH16;
    int gz    = blockIdx.x / NCH16;
    int d0 = chunk * DCH16;
    int nv = min(DCH16, DD3 - d0);       // 16 (15 for the last chunk)
    size_t pbase = (size_t)gz * GG2 * DD3 + d0;

    // fill: global [gp][dd] (dd-fast lanes -> full-line coalesced) -> LDS [dd][gp]
    for (int idx = tid; idx < GG2 * DCH16; idx += 512) {
        int gp = idx >> 4, dd = idx & 15;
        if (dd < nv) T[dd * TST + gp] = in[pbase + (size_t)gp * DD3 + dd];
    }
    __syncthreads();

    float o[29];
    int cgx = -1, cdd = 0;
    if (tid < 29 * nv) {
        cgx = tid % 29; cdd = tid / 29;
        const float* Tb = T + cdd * TST;
        int xm2 = cgx-2 < 0 ? 0 : cgx-2, xm1 = cgx-1 < 0 ? 0 : cgx-1;
        int xp1 = cgx+1 > 28 ? 28 : cgx+1, xp2 = cgx+2 > 28 ? 28 : cgx+2;
        float X[29];
        #pragma unroll
        for (int j = 0; j < 29; ++j) {
            int rb = j * 29;
            X[j] = MW0*(Tb[rb+xm2] + Tb[rb+xp2]) + MW1*(Tb[rb+xm1] + Tb[rb+xp1])
                 + MW2* Tb[rb+cgx];
        }
        #pragma unroll
        for (int gy = 0; gy < 29; ++gy) {
            int ym2 = gy-2 < 0 ? 0 : gy-2, ym1 = gy-1 < 0 ? 0 : gy-1;
            int yp1 = gy+1 > 28 ? 28 : gy+1, yp2 = gy+2 > 28 ? 28 : gy+2;
            o[gy] = MW0*(X[ym2] + X[yp2]) + MW1*(X[ym1] + X[yp1]) + MW2*X[gy];
        }
    }
    __syncthreads();
    if (cgx >= 0) {
        float* Tb = T + cdd * TST;
        #pragma unroll
        for (int gy = 0; gy < 29; ++gy) Tb[gy * 29 + cgx] = o[gy];
    }
    __syncthreads();
    // copy-out (coalesced, same mapping as fill)
    for (int idx = tid; idx < GG2 * DCH16; idx += 512) {
        int gp = idx >> 4, dd = idx & 15;
        if (dd < nv) out[pbase + (size_t)gp * DD3 + dd] = T[dd * TST + gp];
    }
}

// ---------------- K4: z-conv of t2 + combine with dc + minavg_disp -> c3 ----------------
__global__ void __launch_bounds__(256) k_zcomb2(const float* __restrict__ t2,
                                                const float* __restrict__ dcin,
                                                const float* __restrict__ alpha,
                                                float* c3out) {
    __shared__ __align__(16) float U[5776];
    __shared__ __align__(16) float V[5700];
    int tid = threadIdx.x;
    int g = blockIdx.x;
    int gx = g % GG; int gy = (g / GG) % GG; int gz = g / GG2;
    float a2 = alpha[2], a3 = alpha[3], a4 = alpha[4];
    size_t rb0 = ((size_t)((clampi(gz-2,0,28)*GG + gy)*GG + gx)) * DD3;
    size_t rb1 = ((size_t)((clampi(gz-1,0,28)*GG + gy)*GG + gx)) * DD3;
    size_t rb2 = ((size_t)((gz*GG + gy)*GG + gx)) * DD3;
    size_t rb3 = ((size_t)((clampi(gz+1,0,28)*GG + gy)*GG + gx)) * DD3;
    size_t rb4 = ((size_t)((clampi(gz+2,0,28)*GG + gy)*GG + gx)) * DD3;
    const float* drow = dcin + (size_t)g * DD3;
    float v[15];
    if (tid < 225) {
        #pragma unroll
        for (int z = 0; z < 15; ++z) {
            int d = z*225 + tid;
            float ca = MW0*(t2[rb0+d] + t2[rb4+d]) + MW1*(t2[rb1+d] + t2[rb3+d])
                     + MW2*t2[rb2+d];
            v[z] = a4 + a2 * drow[d] + a3 * ca;
        }
    }
    minavg_cols(U, V, v, tid, c3out + (size_t)g * DD3);
}

// ---------------- K7: z-conv of t4 -> softmax -> cost_soft + pred_xyz ----------------
__global__ void __launch_bounds__(256) k_zsoftmax(const float* __restrict__ t4,
                                                  const float* __restrict__ alpha,
                                                  float* __restrict__ cost,
                                                  float* __restrict__ pred) {
    __shared__ float row[DD3];
    __shared__ float4 red4[256];
    int tid = threadIdx.x;
    int g = blockIdx.x;
    int gx = g % GG; int gy = (g / GG) % GG; int gz = g / GG2;
    float a5 = alpha[5];
    size_t rb0 = ((size_t)((clampi(gz-2,0,28)*GG + gy)*GG + gx)) * DD3;
    size_t rb1 = ((size_t)((clampi(gz-1,0,28)*GG + gy)*GG + gx)) * DD3;
    size_t rb2 = ((size_t)((gz*GG + gy)*GG + gx)) * DD3;
    size_t rb3 = ((size_t)((clampi(gz+1,0,28)*GG + gy)*GG + gx)) * DD3;
    size_t rb4 = ((size_t)((clampi(gz+2,0,28)*GG + gy)*GG + gx)) * DD3;

    float lmax = -3.0e38f;
    for (int d = tid; d < DD3; d += 256) {
        float ca = MW0*(t4[rb0+d] + t4[rb4+d]) + MW1*(t4[rb1+d] + t4[rb3+d]) + MW2*t4[rb2+d];
        float vv = -a5 * ca;
        row[d] = vv;
        lmax = fmaxf(lmax, vv);
    }
    red4[tid].x = lmax;
    __syncthreads();
    for (int s = 128; s > 0; s >>= 1) {
        if (tid < s) red4[tid].x = fmaxf(red4[tid].x, red4[tid + s].x);
        __syncthreads();
    }
    float m = red4[0].x;
    __syncthreads();

    float s0 = 0.f, s1 = 0.f, s2 = 0.f, s3 = 0.f;
    for (int d = tid; d < DD3; d += 256) {
        float p = expf(row[d] - m);
        row[d] = p;
        int jx = d % 15; int r = d / 15; int jy = r % 15; int jz = r / 15;
        s0 += p;
        s1 += p * (0.4f * ((2.0f * jx + 1.0f) / 15.0f - 1.0f));
        s2 += p * (0.4f * ((2.0f * jy + 1.0f) / 15.0f - 1.0f));
        s3 += p * (0.4f * ((2.0f * jz + 1.0f) / 15.0f - 1.0f));
    }
    red4[tid] = make_float4(s0, s1, s2, s3);
    __syncthreads();
    for (int s = 128; s > 0; s >>= 1) {
        if (tid < s) {
            float4 a = red4[tid], b = red4[tid + s];
            red4[tid] = make_float4(a.x + b.x, a.y + b.y, a.z + b.z, a.w + b.w);
        }
        __syncthreads();
    }
    float4 tot = red4[0];
    float inv = 1.0f / tot.x;
    size_t base = (size_t)g * DD3;
    for (int d = tid; d < DD3; d += 256) cost[base + d] = row[d] * inv;
    if (tid == 0) {
        pred[g*3 + 0] = tot.y * inv;
        pred[g*3 + 1] = tot.z * inv;
        pred[g*3 + 2] = tot.w * inv;
    }
}

extern "C" void kernel_launch(void* const* d_in, const int* in_sizes, int n_in,
                              void* d_out, int out_size, void* d_ws, size_t ws_size,
                              hipStream_t stream) {
    const float* feat00 = (const float*)d_in[0];
    const float* feat50 = (const float*)d_in[1];
    const float* alpha  = (const float*)d_in[2];
    float* out = (float*)d_out;
    float* ws  = (float*)d_ws;

    float* ft5  = ws;                            // [4][NVOX] float4 (FT_ELEMS floats)
    float* S0   = ws + FT_ELEMS;                 // dc -> c3 -> t4 (row-local reuse)
    float* DOUT = out;                           // scratch use of output buffer: c -> t2
    float* pred = out + (size_t)GG3 * DD3;

    size_t need = ((size_t)FT_ELEMS + (size_t)GG3 * DD3) * sizeof(float);
    if (ws_size < need) return;  // fail cleanly if workspace too small

    // moving image: voxel-major channel-quad layout for LDS window staging
    k_transpose4<<<dim3(NVOX / 256, 4), 256, 0, stream>>>(feat50, ft5);

    // dc
    k_cost4<<<GG3, 256, 0, stream>>>(ft5, feat00, alpha, S0);
    // c = minavg_disp(dc)
    k_minavg2<<<GG3, 256, 0, stream>>>(S0, DOUT);
    // avg_grid x,y on c (fused, coalesced, in-place; z-conv folded into next kernel)
    k_convxy2<<<GG * NCH16, 512, 0, stream>>>(DOUT, DOUT);
    // c3 = minavg_disp(a4 + a2*dc + a3*zconv(t2))
    k_zcomb2<<<GG3, 256, 0, stream>>>(DOUT, S0, alpha, S0);
    // avg_grid x,y on c3 (fused, in-place)
    k_convxy2<<<GG * NCH16, 512, 0, stream>>>(S0, S0);
    // z-conv + softmax + pred
    k_zsoftmax<<<GG3, 256, 0, stream>>>(S0, alpha, out, pred);
}